// Round 1
// baseline (3402.628 us; speedup 1.0000x reference)
//
#include <hip/hip_runtime.h>
#include <math.h>

#define BB 16
#define H 1024
#define W 1024
#define HW (H*W)
#define NTOT (BB*HW)

// float32 of np.exp(-0.5*(n/1)^2), n=-2..2 (correctly-rounded decimal literals)
__device__ __constant__ float GW[5] = {
    0.13533528323661270f, 0.60653065971263342f, 1.0f,
    0.60653065971263342f, 0.13533528323661270f};

// NMS neighbor offsets per direction bucket (cross-correlation mapping of DIR_FILT)
// 0:E 1:SE 2:S 3:SW 4:W 5:NW 6:N 7:NE
__device__ __constant__ int NBDY[8] = {0, 1, 1, 1, 0, -1, -1, -1};
__device__ __constant__ int NBDX[8] = {1, 1, 0, -1, -1, -1, 0, 1};

#define CSCALE ((float)(180.0 / 3.1415926))

// ---------------- Gaussian horizontal (1x5, zero pad) ----------------
__global__ __launch_bounds__(256) void k_gauss_h(const float* __restrict__ in,
                                                 float* __restrict__ out) {
#pragma clang fp contract(off)
    const int i = blockIdx.x * 256 + threadIdx.x;
    const int x = i & (W - 1);
    float s = 0.0f;
#pragma unroll
    for (int k = 0; k < 5; ++k) {
        int xx = x + k - 2;
        float v = (xx >= 0 && xx < W) ? in[i + (k - 2)] : 0.0f;
        s = s + GW[k] * v;
    }
    out[i] = s;
}

// ---------------- Gaussian vertical (5x1, zero pad) ----------------
__global__ __launch_bounds__(256) void k_gauss_v(const float* __restrict__ in,
                                                 float* __restrict__ out) {
#pragma clang fp contract(off)
    const int i = blockIdx.x * 256 + threadIdx.x;
    const int y = (i >> 10) & (H - 1);
    float s = 0.0f;
#pragma unroll
    for (int k = 0; k < 5; ++k) {
        int yy = y + k - 2;
        float v = (yy >= 0 && yy < H) ? in[i + (k - 2) * W] : 0.0f;
        s = s + GW[k] * v;
    }
    out[i] = s;
}

// ---------------- Sobel + magnitude + direction bucket + per-image max ----------------
__global__ __launch_bounds__(256) void k_sobel(const float* __restrict__ sm,
                                               float* __restrict__ mag,
                                               unsigned char* __restrict__ bucket,
                                               unsigned int* __restrict__ magmax) {
#pragma clang fp contract(off)
    const int i = blockIdx.x * 256 + threadIdx.x;
    const int x = i & (W - 1);
    const int y = (i >> 10) & (H - 1);
    const int b = i >> 20;
    const size_t base = (size_t)b * HW;

    float a00 = 0.f, a01 = 0.f, a02 = 0.f, a10 = 0.f, a12 = 0.f, a20 = 0.f, a21 = 0.f, a22 = 0.f;
    const bool ym = (y > 0), yp = (y < H - 1), xm = (x > 0), xp = (x < W - 1);
    const size_t o = base + (size_t)y * W + x;
    if (ym) {
        if (xm) a00 = sm[o - W - 1];
        a01 = sm[o - W];
        if (xp) a02 = sm[o - W + 1];
    }
    if (xm) a10 = sm[o - 1];
    if (xp) a12 = sm[o + 1];
    if (yp) {
        if (xm) a20 = sm[o + W - 1];
        a21 = sm[o + W];
        if (xp) a22 = sm[o + W + 1];
    }

    // row-major sequential accumulation, no FMA (matches separate mul+add)
    float Ix = a00;
    Ix = Ix - a02;
    Ix = Ix + 2.0f * a10;
    Ix = Ix - 2.0f * a12;
    Ix = Ix + a20;
    Ix = Ix - a22;

    float Iy = a00;
    Iy = Iy + 2.0f * a01;
    Iy = Iy + a02;
    Iy = Iy - a20;
    Iy = Iy - 2.0f * a21;
    Iy = Iy - a22;

    float t1 = Ix * Ix;
    float t2 = Iy * Iy;
    float m = sqrtf(t1 + t2);
    mag[i] = m;

    // direction bucket: round((atan2*C + 180)/45) % 8, half-to-even
    float fa = atan2f(Iy, Ix);
    float d = fa * CSCALE;
    d = d + 180.0f;
    float t = d / 45.0f;
    float r = rintf(t);
    if (0.5f - fabsf(t - r) < 1e-4f) {
        // near a rounding boundary: redo with correctly-rounded float32 atan2
        float fa2 = (float)atan2((double)Iy, (double)Ix);
        float d2 = fa2 * CSCALE;
        d2 = d2 + 180.0f;
        float t2d = d2 / 45.0f;
        r = rintf(t2d);
    }
    int idx = ((int)r) % 8;
    bucket[i] = (unsigned char)idx;

    // per-image max(mag) (mag >= 0, float bits order-isomorphic to uint)
    __shared__ float red[256];
    red[threadIdx.x] = m;
    __syncthreads();
    for (int s = 128; s > 0; s >>= 1) {
        if (threadIdx.x < s) red[threadIdx.x] = fmaxf(red[threadIdx.x], red[threadIdx.x + s]);
        __syncthreads();
    }
    if (threadIdx.x == 0) atomicMax(&magmax[b], __float_as_uint(red[0]));
}

// ---------------- NMS on normalized magnitude + thin + global thin max ----------------
__global__ __launch_bounds__(256) void k_nms(const float* __restrict__ mag,
                                             const unsigned char* __restrict__ bucket,
                                             const unsigned int* __restrict__ magmax,
                                             float* __restrict__ thin,
                                             unsigned int* __restrict__ thinmax) {
#pragma clang fp contract(off)
    const int i = blockIdx.x * 256 + threadIdx.x;
    const int x = i & (W - 1);
    const int y = (i >> 10) & (H - 1);
    const int b = i >> 20;
    const size_t base = (size_t)b * HW;

    const float M = __uint_as_float(magmax[b]);
    const float mp = mag[i] / M;   // exact replication of reference's normalize division
    const int idx = bucket[i];
    const int dy = NBDY[idx], dx = NBDX[idx];

    float npv = 0.0f, nnv = 0.0f;
    {
        int yy = y + dy, xx = x + dx;
        if (yy >= 0 && yy < H && xx >= 0 && xx < W)
            npv = mag[base + (size_t)yy * W + xx] / M;
        int y2 = y - dy, x2 = x - dx;
        if (y2 >= 0 && y2 < H && x2 >= 0 && x2 < W)
            nnv = mag[base + (size_t)y2 * W + x2] / M;
    }
    float cs_p = mp - npv;
    float cs_n = mp - nnv;
    float tv = (fminf(cs_p, cs_n) > 0.0f) ? mp : 0.0f;
    thin[i] = tv;

    __shared__ float red[256];
    red[threadIdx.x] = tv;
    __syncthreads();
    for (int s = 128; s > 0; s >>= 1) {
        if (threadIdx.x < s) red[threadIdx.x] = fmaxf(red[threadIdx.x], red[threadIdx.x + s]);
        __syncthreads();
    }
    if (threadIdx.x == 0) atomicMax(thinmax, __float_as_uint(red[0]));
}

// ---------------- double threshold -> labels {0,1=weak,2=strong} ----------------
__global__ __launch_bounds__(256) void k_thresh(const float* __restrict__ thin,
                                                const unsigned int* __restrict__ thinmax,
                                                unsigned char* __restrict__ lab) {
#pragma clang fp contract(off)
    const int i = blockIdx.x * 256 + threadIdx.x;
    const float hi = __uint_as_float(*thinmax) * 0.15f;
    const float t = thin[i];
    lab[i] = (t >= hi) ? (unsigned char)2 : ((t >= 0.00392f) ? (unsigned char)1 : (unsigned char)0);
}

// ---------------- hysteresis: 64x64 LDS tile, iterate to local fixpoint ----------------
__global__ __launch_bounds__(256) void k_hyster(unsigned char* __restrict__ lab) {
    __shared__ unsigned char s[66 * 66];
    __shared__ int changed;
    const int b = blockIdx.z;
    const int x0 = blockIdx.x * 64, y0 = blockIdx.y * 64;
    const size_t base = (size_t)b * HW;

    for (int idx = threadIdx.x; idx < 66 * 66; idx += 256) {
        int ly = idx / 66, lx = idx % 66;
        int gy = y0 + ly - 1, gx = x0 + lx - 1;
        unsigned char v = 0;
        if (gy >= 0 && gy < H && gx >= 0 && gx < W) v = lab[base + (size_t)gy * W + gx];
        s[idx] = v;
    }
    __syncthreads();

    for (int it = 0; it < 96; ++it) {
        if (threadIdx.x == 0) changed = 0;
        __syncthreads();
        bool any = false;
#pragma unroll
        for (int k = 0; k < 16; ++k) {
            int c = threadIdx.x + k * 256;
            int ly = (c >> 6) + 1, lx = (c & 63) + 1;
            int o = ly * 66 + lx;
            if (s[o] == 1) {
                if (s[o - 67] == 2 || s[o - 66] == 2 || s[o - 65] == 2 ||
                    s[o - 1] == 2 || s[o + 1] == 2 ||
                    s[o + 65] == 2 || s[o + 66] == 2 || s[o + 67] == 2) {
                    s[o] = 2;
                    any = true;
                }
            }
        }
        if (any) changed = 1;
        __syncthreads();
        if (!changed) break;
    }

    for (int k = 0; k < 16; ++k) {
        int c = threadIdx.x + k * 256;
        int ly = (c >> 6), lx = (c & 63);
        lab[base + (size_t)(y0 + ly) * W + (x0 + lx)] = s[(ly + 1) * 66 + (lx + 1)];
    }
}

// ---------------- finalize: strong->255 else 0 ----------------
__global__ __launch_bounds__(256) void k_final(const unsigned char* __restrict__ lab,
                                               float* __restrict__ out) {
    const int i = blockIdx.x * 256 + threadIdx.x;
    out[i] = (lab[i] == 2) ? 255.0f : 0.0f;
}

extern "C" void kernel_launch(void* const* d_in, const int* in_sizes, int n_in,
                              void* d_out, int out_size, void* d_ws, size_t ws_size,
                              hipStream_t stream) {
    (void)in_sizes; (void)n_in; (void)out_size; (void)ws_size;
    const float* img = (const float*)d_in[0];
    float* out = (float*)d_out;

    unsigned int* hdr = (unsigned int*)d_ws;            // [0..15]=magmax per image, [16]=thinmax
    float* A = (float*)((char*)d_ws + 256);             // 64 MB float scratch
    unsigned char* C = (unsigned char*)((char*)d_ws + 256 + sizeof(float) * (size_t)NTOT);  // 16.7 MB

    hipMemsetAsync(d_ws, 0, 256, stream);

    dim3 blk(256), grd(NTOT / 256);
    k_gauss_h<<<grd, blk, 0, stream>>>(img, A);
    k_gauss_v<<<grd, blk, 0, stream>>>(A, out);          // out = smoothed
    k_sobel<<<grd, blk, 0, stream>>>(out, A, C, hdr);    // A = mag, C = bucket
    k_nms<<<grd, blk, 0, stream>>>(A, C, hdr, out, hdr + 16);  // out = thin
    k_thresh<<<grd, blk, 0, stream>>>(out, hdr + 16, C); // C = labels
    dim3 hgrd(W / 64, H / 64, BB);
    for (int p = 0; p < 6; ++p) k_hyster<<<hgrd, blk, 0, stream>>>(C);
    k_final<<<grd, blk, 0, stream>>>(C, out);
}

// Round 2
// 721.615 us; speedup vs baseline: 4.7153x; 4.7153x over previous
//
#include <hip/hip_runtime.h>
#include <math.h>

#define BB 16
#define H 1024
#define W 1024
#define HW (H*W)
#define NTOT (BB*HW)
#define NBLK (NTOT/256)          // 65536 blocks
#define BLK_PER_IMG (HW/256)     // 4096 blocks per image

// float32 of np.exp(-0.5*(n/1)^2), n=-2..2 (correctly-rounded decimal literals)
__device__ __constant__ float GW[5] = {
    0.13533528323661270f, 0.60653065971263342f, 1.0f,
    0.60653065971263342f, 0.13533528323661270f};

// NMS neighbor offsets per direction bucket (cross-correlation mapping of DIR_FILT)
// 0:E 1:SE 2:S 3:SW 4:W 5:NW 6:N 7:NE
__device__ __constant__ int NBDY[8] = {0, 1, 1, 1, 0, -1, -1, -1};
__device__ __constant__ int NBDX[8] = {1, 1, 0, -1, -1, -1, 0, 1};

#define CSCALE ((float)(180.0 / 3.1415926))

// ---------------- Gaussian horizontal (1x5, zero pad) ----------------
__global__ __launch_bounds__(256) void k_gauss_h(const float* __restrict__ in,
                                                 float* __restrict__ out) {
#pragma clang fp contract(off)
    const int i = blockIdx.x * 256 + threadIdx.x;
    const int x = i & (W - 1);
    float s = 0.0f;
#pragma unroll
    for (int k = 0; k < 5; ++k) {
        int xx = x + k - 2;
        float v = (xx >= 0 && xx < W) ? in[i + (k - 2)] : 0.0f;
        s = s + GW[k] * v;
    }
    out[i] = s;
}

// ---------------- Gaussian vertical (5x1, zero pad) ----------------
__global__ __launch_bounds__(256) void k_gauss_v(const float* __restrict__ in,
                                                 float* __restrict__ out) {
#pragma clang fp contract(off)
    const int i = blockIdx.x * 256 + threadIdx.x;
    const int y = (i >> 10) & (H - 1);
    float s = 0.0f;
#pragma unroll
    for (int k = 0; k < 5; ++k) {
        int yy = y + k - 2;
        float v = (yy >= 0 && yy < H) ? in[i + (k - 2) * W] : 0.0f;
        s = s + GW[k] * v;
    }
    out[i] = s;
}

// ---------------- Sobel + magnitude + direction bucket + per-block max ----------------
__global__ __launch_bounds__(256) void k_sobel(const float* __restrict__ sm,
                                               float* __restrict__ mag,
                                               unsigned char* __restrict__ bucket,
                                               float* __restrict__ partial) {
#pragma clang fp contract(off)
    const int i = blockIdx.x * 256 + threadIdx.x;
    const int x = i & (W - 1);
    const int y = (i >> 10) & (H - 1);
    const int b = i >> 20;
    const size_t base = (size_t)b * HW;

    float a00 = 0.f, a01 = 0.f, a02 = 0.f, a10 = 0.f, a12 = 0.f, a20 = 0.f, a21 = 0.f, a22 = 0.f;
    const bool ym = (y > 0), yp = (y < H - 1), xm = (x > 0), xp = (x < W - 1);
    const size_t o = base + (size_t)y * W + x;
    if (ym) {
        if (xm) a00 = sm[o - W - 1];
        a01 = sm[o - W];
        if (xp) a02 = sm[o - W + 1];
    }
    if (xm) a10 = sm[o - 1];
    if (xp) a12 = sm[o + 1];
    if (yp) {
        if (xm) a20 = sm[o + W - 1];
        a21 = sm[o + W];
        if (xp) a22 = sm[o + W + 1];
    }

    // row-major sequential accumulation, no FMA (matches separate mul+add)
    float Ix = a00;
    Ix = Ix - a02;
    Ix = Ix + 2.0f * a10;
    Ix = Ix - 2.0f * a12;
    Ix = Ix + a20;
    Ix = Ix - a22;

    float Iy = a00;
    Iy = Iy + 2.0f * a01;
    Iy = Iy + a02;
    Iy = Iy - a20;
    Iy = Iy - 2.0f * a21;
    Iy = Iy - a22;

    float t1 = Ix * Ix;
    float t2 = Iy * Iy;
    float m = sqrtf(t1 + t2);
    mag[i] = m;

    // direction bucket: round((atan2*C + 180)/45) % 8, half-to-even
    float fa = atan2f(Iy, Ix);
    float d = fa * CSCALE;
    d = d + 180.0f;
    float t = d / 45.0f;
    float r = rintf(t);
    if (0.5f - fabsf(t - r) < 1e-4f) {
        // near a rounding boundary: redo with correctly-rounded float32 atan2
        float fa2 = (float)atan2((double)Iy, (double)Ix);
        float d2 = fa2 * CSCALE;
        d2 = d2 + 180.0f;
        float t2d = d2 / 45.0f;
        r = rintf(t2d);
    }
    int idx = ((int)r) % 8;
    bucket[i] = (unsigned char)idx;

    // per-block max -> plain store (no atomic storm)
    __shared__ float red[256];
    red[threadIdx.x] = m;
    __syncthreads();
    for (int s = 128; s > 0; s >>= 1) {
        if (threadIdx.x < s) red[threadIdx.x] = fmaxf(red[threadIdx.x], red[threadIdx.x + s]);
        __syncthreads();
    }
    if (threadIdx.x == 0) partial[blockIdx.x] = red[0];
}

// ---------------- per-image max over 4096 block partials ----------------
__global__ __launch_bounds__(256) void k_redmax_img(const float* __restrict__ partial,
                                                    float* __restrict__ magmax) {
    __shared__ float red[256];
    const float* p = partial + (size_t)blockIdx.x * BLK_PER_IMG;
    float m = 0.0f;
    for (int k = threadIdx.x; k < BLK_PER_IMG; k += 256) m = fmaxf(m, p[k]);
    red[threadIdx.x] = m;
    __syncthreads();
    for (int s = 128; s > 0; s >>= 1) {
        if (threadIdx.x < s) red[threadIdx.x] = fmaxf(red[threadIdx.x], red[threadIdx.x + s]);
        __syncthreads();
    }
    if (threadIdx.x == 0) magmax[blockIdx.x] = red[0];
}

// ---------------- global max over all 65536 block partials ----------------
__global__ __launch_bounds__(1024) void k_redmax_all(const float* __restrict__ partial,
                                                     float* __restrict__ thinmax) {
    __shared__ float red[1024];
    float m = 0.0f;
    for (int k = threadIdx.x; k < NBLK; k += 1024) m = fmaxf(m, partial[k]);
    red[threadIdx.x] = m;
    __syncthreads();
    for (int s = 512; s > 0; s >>= 1) {
        if (threadIdx.x < s) red[threadIdx.x] = fmaxf(red[threadIdx.x], red[threadIdx.x + s]);
        __syncthreads();
    }
    if (threadIdx.x == 0) *thinmax = red[0];
}

// ---------------- NMS on normalized magnitude + thin + per-block max ----------------
__global__ __launch_bounds__(256) void k_nms(const float* __restrict__ mag,
                                             const unsigned char* __restrict__ bucket,
                                             const float* __restrict__ magmax,
                                             float* __restrict__ thin,
                                             float* __restrict__ partial) {
#pragma clang fp contract(off)
    const int i = blockIdx.x * 256 + threadIdx.x;
    const int x = i & (W - 1);
    const int y = (i >> 10) & (H - 1);
    const int b = i >> 20;
    const size_t base = (size_t)b * HW;

    const float M = magmax[b];
    const float mp = mag[i] / M;   // exact replication of reference's normalize division
    const int idx = bucket[i];
    const int dy = NBDY[idx], dx = NBDX[idx];

    float npv = 0.0f, nnv = 0.0f;
    {
        int yy = y + dy, xx = x + dx;
        if (yy >= 0 && yy < H && xx >= 0 && xx < W)
            npv = mag[base + (size_t)yy * W + xx] / M;
        int y2 = y - dy, x2 = x - dx;
        if (y2 >= 0 && y2 < H && x2 >= 0 && x2 < W)
            nnv = mag[base + (size_t)y2 * W + x2] / M;
    }
    float cs_p = mp - npv;
    float cs_n = mp - nnv;
    float tv = (fminf(cs_p, cs_n) > 0.0f) ? mp : 0.0f;
    thin[i] = tv;

    __shared__ float red[256];
    red[threadIdx.x] = tv;
    __syncthreads();
    for (int s = 128; s > 0; s >>= 1) {
        if (threadIdx.x < s) red[threadIdx.x] = fmaxf(red[threadIdx.x], red[threadIdx.x + s]);
        __syncthreads();
    }
    if (threadIdx.x == 0) partial[blockIdx.x] = red[0];
}

// ---------------- double threshold -> labels {0,1=weak,2=strong} ----------------
__global__ __launch_bounds__(256) void k_thresh(const float* __restrict__ thin,
                                                const float* __restrict__ thinmax,
                                                unsigned char* __restrict__ lab) {
#pragma clang fp contract(off)
    const int i = blockIdx.x * 256 + threadIdx.x;
    const float hi = (*thinmax) * 0.15f;
    const float t = thin[i];
    lab[i] = (t >= hi) ? (unsigned char)2 : ((t >= 0.00392f) ? (unsigned char)1 : (unsigned char)0);
}

// ---------------- hysteresis: 64x64 LDS tile, iterate to local fixpoint ----------------
__global__ __launch_bounds__(256) void k_hyster(unsigned char* __restrict__ lab) {
    __shared__ unsigned char s[66 * 66];
    __shared__ int changed;
    const int b = blockIdx.z;
    const int x0 = blockIdx.x * 64, y0 = blockIdx.y * 64;
    const size_t base = (size_t)b * HW;

    for (int idx = threadIdx.x; idx < 66 * 66; idx += 256) {
        int ly = idx / 66, lx = idx % 66;
        int gy = y0 + ly - 1, gx = x0 + lx - 1;
        unsigned char v = 0;
        if (gy >= 0 && gy < H && gx >= 0 && gx < W) v = lab[base + (size_t)gy * W + gx];
        s[idx] = v;
    }
    __syncthreads();

    for (int it = 0; it < 96; ++it) {
        if (threadIdx.x == 0) changed = 0;
        __syncthreads();
        bool any = false;
#pragma unroll
        for (int k = 0; k < 16; ++k) {
            int c = threadIdx.x + k * 256;
            int ly = (c >> 6) + 1, lx = (c & 63) + 1;
            int o = ly * 66 + lx;
            if (s[o] == 1) {
                if (s[o - 67] == 2 || s[o - 66] == 2 || s[o - 65] == 2 ||
                    s[o - 1] == 2 || s[o + 1] == 2 ||
                    s[o + 65] == 2 || s[o + 66] == 2 || s[o + 67] == 2) {
                    s[o] = 2;
                    any = true;
                }
            }
        }
        if (any) changed = 1;
        __syncthreads();
        if (!changed) break;
    }

    for (int k = 0; k < 16; ++k) {
        int c = threadIdx.x + k * 256;
        int ly = (c >> 6), lx = (c & 63);
        lab[base + (size_t)(y0 + ly) * W + (x0 + lx)] = s[(ly + 1) * 66 + (lx + 1)];
    }
}

// ---------------- finalize: strong->255 else 0 ----------------
__global__ __launch_bounds__(256) void k_final(const unsigned char* __restrict__ lab,
                                               float* __restrict__ out) {
    const int i = blockIdx.x * 256 + threadIdx.x;
    out[i] = (lab[i] == 2) ? 255.0f : 0.0f;
}

extern "C" void kernel_launch(void* const* d_in, const int* in_sizes, int n_in,
                              void* d_out, int out_size, void* d_ws, size_t ws_size,
                              hipStream_t stream) {
    (void)in_sizes; (void)n_in; (void)out_size; (void)ws_size;
    const float* img = (const float*)d_in[0];
    float* out = (float*)d_out;

    // workspace layout
    float* hdr = (float*)d_ws;                                   // [0..15]=magmax, [16]=thinmax
    float* partial = (float*)((char*)d_ws + 256);                // 65536 floats = 256 KB
    float* A = (float*)((char*)d_ws + 256 + sizeof(float) * (size_t)NBLK);
    unsigned char* C = (unsigned char*)((char*)A + sizeof(float) * (size_t)NTOT);

    dim3 blk(256), grd(NBLK);
    k_gauss_h<<<grd, blk, 0, stream>>>(img, A);
    k_gauss_v<<<grd, blk, 0, stream>>>(A, out);            // out = smoothed
    k_sobel<<<grd, blk, 0, stream>>>(out, A, C, partial);  // A = mag, C = bucket
    k_redmax_img<<<dim3(BB), blk, 0, stream>>>(partial, hdr);
    k_nms<<<grd, blk, 0, stream>>>(A, C, hdr, out, partial);  // out = thin
    k_redmax_all<<<dim3(1), dim3(1024), 0, stream>>>(partial, hdr + 16);
    k_thresh<<<grd, blk, 0, stream>>>(out, hdr + 16, C);   // C = labels
    dim3 hgrd(W / 64, H / 64, BB);
    for (int p = 0; p < 6; ++p) k_hyster<<<hgrd, blk, 0, stream>>>(C);
    k_final<<<grd, blk, 0, stream>>>(C, out);
}

// Round 3
// 436.449 us; speedup vs baseline: 7.7962x; 1.6534x over previous
//
#include <hip/hip_runtime.h>
#include <math.h>

#define BB 16
#define H 1024
#define W 1024
#define HW (H*W)
#define NTOT (BB*HW)
#define NBLK (NTOT/256)          // 65536 blocks
#define BLK_PER_IMG (HW/256)     // 4096 blocks per image
#define WPR 16                   // u64 words per row (1024/64)
#define WPI (H*WPR)              // u64 words per image

typedef unsigned long long u64;

// float32 of np.exp(-0.5*(n/1)^2), n=-2..2 (correctly-rounded decimal literals)
__device__ __constant__ float GW[5] = {
    0.13533528323661270f, 0.60653065971263342f, 1.0f,
    0.60653065971263342f, 0.13533528323661270f};

// NMS neighbor offsets per direction bucket (cross-correlation mapping of DIR_FILT)
// 0:E 1:SE 2:S 3:SW 4:W 5:NW 6:N 7:NE
__device__ __constant__ int NBDY[8] = {0, 1, 1, 1, 0, -1, -1, -1};
__device__ __constant__ int NBDX[8] = {1, 1, 0, -1, -1, -1, 0, 1};

#define CSCALE ((float)(180.0 / 3.1415926))

// ---------------- Gaussian horizontal (1x5, zero pad) ----------------
__global__ __launch_bounds__(256) void k_gauss_h(const float* __restrict__ in,
                                                 float* __restrict__ out) {
#pragma clang fp contract(off)
    const int i = blockIdx.x * 256 + threadIdx.x;
    const int x = i & (W - 1);
    float s = 0.0f;
#pragma unroll
    for (int k = 0; k < 5; ++k) {
        int xx = x + k - 2;
        float v = (xx >= 0 && xx < W) ? in[i + (k - 2)] : 0.0f;
        s = s + GW[k] * v;
    }
    out[i] = s;
}

// ---------------- Gaussian vertical (5x1, zero pad) ----------------
__global__ __launch_bounds__(256) void k_gauss_v(const float* __restrict__ in,
                                                 float* __restrict__ out) {
#pragma clang fp contract(off)
    const int i = blockIdx.x * 256 + threadIdx.x;
    const int y = (i >> 10) & (H - 1);
    float s = 0.0f;
#pragma unroll
    for (int k = 0; k < 5; ++k) {
        int yy = y + k - 2;
        float v = (yy >= 0 && yy < H) ? in[i + (k - 2) * W] : 0.0f;
        s = s + GW[k] * v;
    }
    out[i] = s;
}

// ---------------- Sobel + magnitude + direction bucket + per-block max ----------------
__global__ __launch_bounds__(256) void k_sobel(const float* __restrict__ sm,
                                               float* __restrict__ mag,
                                               unsigned char* __restrict__ bucket,
                                               float* __restrict__ partial) {
#pragma clang fp contract(off)
    const int i = blockIdx.x * 256 + threadIdx.x;
    const int x = i & (W - 1);
    const int y = (i >> 10) & (H - 1);
    const int b = i >> 20;
    const size_t base = (size_t)b * HW;

    float a00 = 0.f, a01 = 0.f, a02 = 0.f, a10 = 0.f, a12 = 0.f, a20 = 0.f, a21 = 0.f, a22 = 0.f;
    const bool ym = (y > 0), yp = (y < H - 1), xm = (x > 0), xp = (x < W - 1);
    const size_t o = base + (size_t)y * W + x;
    if (ym) {
        if (xm) a00 = sm[o - W - 1];
        a01 = sm[o - W];
        if (xp) a02 = sm[o - W + 1];
    }
    if (xm) a10 = sm[o - 1];
    if (xp) a12 = sm[o + 1];
    if (yp) {
        if (xm) a20 = sm[o + W - 1];
        a21 = sm[o + W];
        if (xp) a22 = sm[o + W + 1];
    }

    // row-major sequential accumulation, no FMA (matches separate mul+add)
    float Ix = a00;
    Ix = Ix - a02;
    Ix = Ix + 2.0f * a10;
    Ix = Ix - 2.0f * a12;
    Ix = Ix + a20;
    Ix = Ix - a22;

    float Iy = a00;
    Iy = Iy + 2.0f * a01;
    Iy = Iy + a02;
    Iy = Iy - a20;
    Iy = Iy - 2.0f * a21;
    Iy = Iy - a22;

    float t1 = Ix * Ix;
    float t2 = Iy * Iy;
    float m = sqrtf(t1 + t2);
    mag[i] = m;

    // direction bucket: round((atan2*C + 180)/45) % 8, half-to-even
    float fa = atan2f(Iy, Ix);
    float d = fa * CSCALE;
    d = d + 180.0f;
    float t = d / 45.0f;
    float r = rintf(t);
    if (0.5f - fabsf(t - r) < 1e-4f) {
        // near a rounding boundary: redo with correctly-rounded float32 atan2
        float fa2 = (float)atan2((double)Iy, (double)Ix);
        float d2 = fa2 * CSCALE;
        d2 = d2 + 180.0f;
        float t2d = d2 / 45.0f;
        r = rintf(t2d);
    }
    int idx = ((int)r) % 8;
    bucket[i] = (unsigned char)idx;

    // per-block max -> plain store (no atomic storm)
    __shared__ float red[256];
    red[threadIdx.x] = m;
    __syncthreads();
    for (int s = 128; s > 0; s >>= 1) {
        if (threadIdx.x < s) red[threadIdx.x] = fmaxf(red[threadIdx.x], red[threadIdx.x + s]);
        __syncthreads();
    }
    if (threadIdx.x == 0) partial[blockIdx.x] = red[0];
}

// ---------------- per-image max over 4096 block partials ----------------
__global__ __launch_bounds__(256) void k_redmax_img(const float* __restrict__ partial,
                                                    float* __restrict__ magmax) {
    __shared__ float red[256];
    const float* p = partial + (size_t)blockIdx.x * BLK_PER_IMG;
    float m = 0.0f;
    for (int k = threadIdx.x; k < BLK_PER_IMG; k += 256) m = fmaxf(m, p[k]);
    red[threadIdx.x] = m;
    __syncthreads();
    for (int s = 128; s > 0; s >>= 1) {
        if (threadIdx.x < s) red[threadIdx.x] = fmaxf(red[threadIdx.x], red[threadIdx.x + s]);
        __syncthreads();
    }
    if (threadIdx.x == 0) magmax[blockIdx.x] = red[0];
}

// ---------------- global max over all 65536 block partials ----------------
__global__ __launch_bounds__(1024) void k_redmax_all(const float* __restrict__ partial,
                                                     float* __restrict__ thinmax) {
    __shared__ float red[1024];
    float m = 0.0f;
    for (int k = threadIdx.x; k < NBLK; k += 1024) m = fmaxf(m, partial[k]);
    red[threadIdx.x] = m;
    __syncthreads();
    for (int s = 512; s > 0; s >>= 1) {
        if (threadIdx.x < s) red[threadIdx.x] = fmaxf(red[threadIdx.x], red[threadIdx.x + s]);
        __syncthreads();
    }
    if (threadIdx.x == 0) *thinmax = red[0];
}

// ---------------- NMS on normalized magnitude + thin + per-block max ----------------
__global__ __launch_bounds__(256) void k_nms(const float* __restrict__ mag,
                                             const unsigned char* __restrict__ bucket,
                                             const float* __restrict__ magmax,
                                             float* __restrict__ thin,
                                             float* __restrict__ partial) {
#pragma clang fp contract(off)
    const int i = blockIdx.x * 256 + threadIdx.x;
    const int x = i & (W - 1);
    const int y = (i >> 10) & (H - 1);
    const int b = i >> 20;
    const size_t base = (size_t)b * HW;

    const float M = magmax[b];
    const float mp = mag[i] / M;   // exact replication of reference's normalize division
    const int idx = bucket[i];
    const int dy = NBDY[idx], dx = NBDX[idx];

    float npv = 0.0f, nnv = 0.0f;
    {
        int yy = y + dy, xx = x + dx;
        if (yy >= 0 && yy < H && xx >= 0 && xx < W)
            npv = mag[base + (size_t)yy * W + xx] / M;
        int y2 = y - dy, x2 = x - dx;
        if (y2 >= 0 && y2 < H && x2 >= 0 && x2 < W)
            nnv = mag[base + (size_t)y2 * W + x2] / M;
    }
    float cs_p = mp - npv;
    float cs_n = mp - nnv;
    float tv = (fminf(cs_p, cs_n) > 0.0f) ? mp : 0.0f;
    thin[i] = tv;

    __shared__ float red[256];
    red[threadIdx.x] = tv;
    __syncthreads();
    for (int s = 128; s > 0; s >>= 1) {
        if (threadIdx.x < s) red[threadIdx.x] = fmaxf(red[threadIdx.x], red[threadIdx.x + s]);
        __syncthreads();
    }
    if (threadIdx.x == 0) partial[blockIdx.x] = red[0];
}

// ---------------- double threshold -> packed strong/weak bitmasks ----------------
__global__ __launch_bounds__(256) void k_thresh(const float* __restrict__ thin,
                                                const float* __restrict__ thinmax,
                                                u64* __restrict__ Sb,
                                                u64* __restrict__ Wb) {
#pragma clang fp contract(off)
    const int i = blockIdx.x * 256 + threadIdx.x;
    const float hi = (*thinmax) * 0.15f;
    const float t = thin[i];
    const bool strong = (t >= hi);
    const bool weak = (!strong) && (t >= 0.00392f);
    u64 sw = __ballot(strong);
    u64 ww = __ballot(weak);
    if ((threadIdx.x & 63) == 0) {
        Sb[i >> 6] = sw;
        Wb[i >> 6] = ww;
    }
}

// ---------------- hysteresis: bit-parallel 64x64 tile per wave ----------------
// lane r holds row r of the tile as a u64 (64 columns). Frozen halo per pass
// (identical semantics to the byte-tile version). No LDS, no syncthreads.
__global__ __launch_bounds__(256) void k_hyster_bits(const u64* __restrict__ Wb,
                                                     u64* __restrict__ Sb) {
    const int lane = threadIdx.x & 63;
    const int t = blockIdx.x * 4 + (threadIdx.x >> 6);   // tile id
    const int b = t >> 8;
    const int ty = (t >> 4) & 15;
    const int tx = t & 15;
    const int y = ty * 64 + lane;
    const int idx = b * WPI + y * WPR + tx;

    u64 S = Sb[idx];
    const u64 Wk = Wb[idx];

    // static horizontal halo bits for this row (left/right neighbor words)
    u64 hstat = 0;
    if (tx > 0)  hstat |= (Sb[idx - 1] >> 63) & 1ull;
    if (tx < 15) hstat |= (Sb[idx + 1] & 1ull) << 63;

    // static vertical halo: lane 0 needs h of the row above the tile,
    // lane 63 needs h of the row below; frozen for the whole pass.
    u64 halo = 0;
    int hy = -1;
    if (lane == 0 && ty > 0) hy = ty * 64 - 1;
    if (lane == 63 && ty < 15) hy = ty * 64 + 64;
    if (hy >= 0) {
        const int hidx = b * WPI + hy * WPR + tx;
        u64 tc = Sb[hidx];
        u64 hh = (tc << 1) | tc | (tc >> 1);
        if (tx > 0)  hh |= (Sb[hidx - 1] >> 63) & 1ull;
        if (tx < 15) hh |= (Sb[hidx + 1] & 1ull) << 63;
        halo = hh;
    }

    for (int it = 0; it < 160; ++it) {
        u64 h = (S << 1) | S | (S >> 1) | hstat;
        u64 up = __shfl_up(h, 1, 64);
        if (lane == 0) up = halo;
        u64 dn = __shfl_down(h, 1, 64);
        if (lane == 63) dn = halo;
        u64 dil = h | up | dn;
        u64 nS = S | (Wk & dil);     // weak & strong disjoint -> center bit harmless
        bool ch = (nS != S);
        S = nS;
        if (!__any(ch)) break;
    }

    Sb[idx] = S;
}

// ---------------- finalize: strong bit -> 255 else 0 ----------------
__global__ __launch_bounds__(256) void k_final(const u64* __restrict__ Sb,
                                               float* __restrict__ out) {
    const int i = blockIdx.x * 256 + threadIdx.x;
    const u64 w = Sb[i >> 6];
    out[i] = ((w >> (i & 63)) & 1ull) ? 255.0f : 0.0f;
}

extern "C" void kernel_launch(void* const* d_in, const int* in_sizes, int n_in,
                              void* d_out, int out_size, void* d_ws, size_t ws_size,
                              hipStream_t stream) {
    (void)in_sizes; (void)n_in; (void)out_size; (void)ws_size;
    const float* img = (const float*)d_in[0];
    float* out = (float*)d_out;

    // workspace layout
    float* hdr = (float*)d_ws;                                   // [0..15]=magmax, [16]=thinmax
    float* partial = (float*)((char*)d_ws + 256);                // 65536 floats = 256 KB
    float* A = (float*)((char*)d_ws + 256 + sizeof(float) * (size_t)NBLK);
    unsigned char* C = (unsigned char*)((char*)A + sizeof(float) * (size_t)NTOT);   // 16 MB buckets
    u64* Sb = (u64*)(C + (size_t)NTOT);                          // 2 MB strong bits
    u64* Wb = Sb + NTOT / 64;                                    // 2 MB weak bits

    dim3 blk(256), grd(NBLK);
    k_gauss_h<<<grd, blk, 0, stream>>>(img, A);
    k_gauss_v<<<grd, blk, 0, stream>>>(A, out);            // out = smoothed
    k_sobel<<<grd, blk, 0, stream>>>(out, A, C, partial);  // A = mag, C = bucket
    k_redmax_img<<<dim3(BB), blk, 0, stream>>>(partial, hdr);
    k_nms<<<grd, blk, 0, stream>>>(A, C, hdr, out, partial);  // out = thin
    k_redmax_all<<<dim3(1), dim3(1024), 0, stream>>>(partial, hdr + 16);
    k_thresh<<<grd, blk, 0, stream>>>(out, hdr + 16, Sb, Wb);
    dim3 hgrd(NTOT / (64 * 64) / 4);                       // 4096 tiles, 4 waves/block
    for (int p = 0; p < 6; ++p) k_hyster_bits<<<hgrd, blk, 0, stream>>>(Wb, Sb);
    k_final<<<grd, blk, 0, stream>>>(Sb, out);
}

// Round 4
// 324.690 us; speedup vs baseline: 10.4796x; 1.3442x over previous
//
#include <hip/hip_runtime.h>
#include <math.h>

#define BB 16
#define H 1024
#define W 1024
#define HW (H*W)
#define NTOT (BB*HW)

typedef unsigned long long u64;

// float32 of np.exp(-0.5*(n/1)^2), n=-2..2 (correctly-rounded decimal literals)
__device__ __constant__ float GW[5] = {
    0.13533528323661270f, 0.60653065971263342f, 1.0f,
    0.60653065971263342f, 0.13533528323661270f};

// NMS neighbor offsets per direction bucket (cross-correlation mapping of DIR_FILT)
// 0:E 1:SE 2:S 3:SW 4:W 5:NW 6:N 7:NE
__device__ __constant__ int NBDY[8] = {0, 1, 1, 1, 0, -1, -1, -1};
__device__ __constant__ int NBDX[8] = {1, 1, 0, -1, -1, -1, 0, 1};

#define CSCALE ((float)(180.0 / 3.1415926))

// =====================================================================
// K1: fused gaussian(h)+gaussian(v)+sobel+mag+bucket + per-block magmax
// Tile: 128 wide x 32 high. LDS staging, float4 global loads.
// Per-element arithmetic is bit-identical to the unfused version.
// =====================================================================
#define TW 128
#define TH 32
// sA: img rows y0-3..y0+34 (38), cols x0-4..x0+131 (136), stride 136
// sB: gh  rows y0-3..y0+34 (38), cols x0-1..x0+130 (130 used), stride 132
// sm overlays sA: rows y0-1..y0+32 (34), cols x0-1..x0+128 (130 used), stride 136
__global__ __launch_bounds__(256) void k_smooth_sobel(const float* __restrict__ img,
                                                      float* __restrict__ mag,
                                                      unsigned char* __restrict__ bucket,
                                                      float* __restrict__ partial) {
#pragma clang fp contract(off)
    __shared__ float sA[38 * 136];
    __shared__ float sB[38 * 132];
    __shared__ float red[256];

    const int tid = threadIdx.x;
    const int x0 = blockIdx.x * TW;
    const int y0 = blockIdx.y * TH;
    const int b = blockIdx.z;
    const size_t base = (size_t)b * HW;

    // ---- stage A: load img tile + halo (float4, all-or-nothing per vec) ----
    for (int idx = tid; idx < 38 * 34; idx += 256) {
        int r = idx / 34, v = idx % 34;
        int gy = y0 - 3 + r;
        int gxv = x0 - 4 + v * 4;
        float4 val = make_float4(0.f, 0.f, 0.f, 0.f);
        if (gy >= 0 && gy < H && gxv >= 0 && gxv < W)
            val = *(const float4*)&img[base + (size_t)gy * W + gxv];
        *(float4*)&sA[r * 136 + v * 4] = val;
    }
    __syncthreads();

    // ---- stage B: horizontal gaussian -> sB ----
    // gh col c <-> global x0-1+c ; img col for x-2+k is sA col c+1+k
    for (int idx = tid; idx < 38 * 130; idx += 256) {
        int r = idx / 130, c = idx % 130;
        const float* row = &sA[r * 136 + c + 1];
        float s = 0.0f;
#pragma unroll
        for (int k = 0; k < 5; ++k) s = s + GW[k] * row[k];
        sB[r * 132 + c] = s;
    }
    __syncthreads();

    // ---- stage C: vertical gaussian -> sm (overlays sA) ----
    // sm row rr <-> global y0-1+rr, uses gh rows rr..rr+4
    for (int idx = tid; idx < 34 * 130; idx += 256) {
        int rr = idx / 130, c = idx % 130;
        float s = 0.0f;
#pragma unroll
        for (int k = 0; k < 5; ++k) s = s + GW[k] * sB[(rr + k) * 132 + c];
        sA[rr * 136 + c] = s;
    }
    __syncthreads();

    // ---- stage D: sobel + mag + direction bucket + block max ----
    float tmax = 0.0f;
#pragma unroll
    for (int k16 = 0; k16 < 16; ++k16) {
        int p = tid + k16 * 256;
        int r = p >> 7, c = p & 127;
        int y = y0 + r, x = x0 + c;
        const bool ym = (y > 0), yp = (y < H - 1), xm = (x > 0), xp = (x < W - 1);

        // sm(y+dy, x+dx) = sA[(r+1+dy)*136 + (c+1+dx)]
        float a00 = 0.f, a01 = 0.f, a02 = 0.f, a10 = 0.f, a12 = 0.f, a20 = 0.f, a21 = 0.f, a22 = 0.f;
        if (ym) {
            if (xm) a00 = sA[r * 136 + c];
            a01 = sA[r * 136 + c + 1];
            if (xp) a02 = sA[r * 136 + c + 2];
        }
        if (xm) a10 = sA[(r + 1) * 136 + c];
        if (xp) a12 = sA[(r + 1) * 136 + c + 2];
        if (yp) {
            if (xm) a20 = sA[(r + 2) * 136 + c];
            a21 = sA[(r + 2) * 136 + c + 1];
            if (xp) a22 = sA[(r + 2) * 136 + c + 2];
        }

        float Ix = a00;
        Ix = Ix - a02;
        Ix = Ix + 2.0f * a10;
        Ix = Ix - 2.0f * a12;
        Ix = Ix + a20;
        Ix = Ix - a22;

        float Iy = a00;
        Iy = Iy + 2.0f * a01;
        Iy = Iy + a02;
        Iy = Iy - a20;
        Iy = Iy - 2.0f * a21;
        Iy = Iy - a22;

        float t1 = Ix * Ix;
        float t2 = Iy * Iy;
        float m = sqrtf(t1 + t2);
        mag[base + (size_t)y * W + x] = m;
        tmax = fmaxf(tmax, m);

        float fa = atan2f(Iy, Ix);
        float d = fa * CSCALE;
        d = d + 180.0f;
        float t = d / 45.0f;
        float rr2 = rintf(t);
        if (0.5f - fabsf(t - rr2) < 1e-4f) {
            float fa2 = (float)atan2((double)Iy, (double)Ix);
            float d2 = fa2 * CSCALE;
            d2 = d2 + 180.0f;
            float t2d = d2 / 45.0f;
            rr2 = rintf(t2d);
        }
        int idx = ((int)rr2) % 8;
        bucket[base + (size_t)y * W + x] = (unsigned char)idx;
    }

    red[tid] = tmax;
    __syncthreads();
    for (int s = 128; s > 0; s >>= 1) {
        if (tid < s) red[tid] = fmaxf(red[tid], red[tid + s]);
        __syncthreads();
    }
    if (tid == 0) {
        int pb = (blockIdx.z * 32 + blockIdx.y) * 8 + blockIdx.x;  // 256 per image
        partial[pb] = red[0];
    }
}

// ---------------- per-image max over 256 block partials ----------------
__global__ __launch_bounds__(256) void k_redmax_img(const float* __restrict__ partial,
                                                    float* __restrict__ magmax) {
    __shared__ float red[256];
    red[threadIdx.x] = partial[blockIdx.x * 256 + threadIdx.x];
    __syncthreads();
    for (int s = 128; s > 0; s >>= 1) {
        if (threadIdx.x < s) red[threadIdx.x] = fmaxf(red[threadIdx.x], red[threadIdx.x + s]);
        __syncthreads();
    }
    if (threadIdx.x == 0) magmax[blockIdx.x] = red[0];
}

// ---------------- global max over 16384 nms-block partials ----------------
__global__ __launch_bounds__(1024) void k_redmax_all(const float* __restrict__ partial,
                                                     float* __restrict__ thinmax) {
    __shared__ float red[1024];
    float m = 0.0f;
    for (int k = threadIdx.x; k < 16384; k += 1024) m = fmaxf(m, partial[k]);
    red[threadIdx.x] = m;
    __syncthreads();
    for (int s = 512; s > 0; s >>= 1) {
        if (threadIdx.x < s) red[threadIdx.x] = fmaxf(red[threadIdx.x], red[threadIdx.x + s]);
        __syncthreads();
    }
    if (threadIdx.x == 0) *thinmax = red[0];
}

// ---------------- NMS, 4 px/thread, float4 I/O + per-block max ----------------
__global__ __launch_bounds__(256) void k_nms4(const float* __restrict__ mag,
                                              const unsigned char* __restrict__ bucket,
                                              const float* __restrict__ magmax,
                                              float* __restrict__ thin,
                                              float* __restrict__ partial) {
#pragma clang fp contract(off)
    const int gid = blockIdx.x * 256 + threadIdx.x;
    const int p0 = gid * 4;
    const int x0 = p0 & (W - 1);
    const int y = (p0 >> 10) & (H - 1);
    const int b = p0 >> 20;
    const size_t base = (size_t)b * HW;

    const float M = magmax[b];
    const float4 m4 = *(const float4*)&mag[p0];
    unsigned int bk4 = *(const unsigned int*)&bucket[p0];

    float tv[4];
    float mv[4] = {m4.x, m4.y, m4.z, m4.w};
#pragma unroll
    for (int j = 0; j < 4; ++j) {
        int x = x0 + j;
        float mp = mv[j] / M;
        int idx = (bk4 >> (8 * j)) & 0xff;
        int dy = NBDY[idx], dx = NBDX[idx];
        float npv = 0.0f, nnv = 0.0f;
        int yy = y + dy, xx = x + dx;
        if (yy >= 0 && yy < H && xx >= 0 && xx < W)
            npv = mag[base + (size_t)yy * W + xx] / M;
        int y2 = y - dy, x2 = x - dx;
        if (y2 >= 0 && y2 < H && x2 >= 0 && x2 < W)
            nnv = mag[base + (size_t)y2 * W + x2] / M;
        float cs_p = mp - npv;
        float cs_n = mp - nnv;
        tv[j] = (fminf(cs_p, cs_n) > 0.0f) ? mp : 0.0f;
    }
    *(float4*)&thin[p0] = make_float4(tv[0], tv[1], tv[2], tv[3]);

    float tmax = fmaxf(fmaxf(tv[0], tv[1]), fmaxf(tv[2], tv[3]));
    __shared__ float red[256];
    red[threadIdx.x] = tmax;
    __syncthreads();
    for (int s = 128; s > 0; s >>= 1) {
        if (threadIdx.x < s) red[threadIdx.x] = fmaxf(red[threadIdx.x], red[threadIdx.x + s]);
        __syncthreads();
    }
    if (threadIdx.x == 0) partial[blockIdx.x] = red[0];
}

// ---------------- double threshold -> tile-major packed bitmasks ----------------
// Tile-major layout: word index = (b*256 + ty*16 + tx)*64 + (y&63)
// One block = one image row (1024 px). 4 px/thread via float4.
__global__ __launch_bounds__(256) void k_thresh4(const float* __restrict__ thin,
                                                 const float* __restrict__ thinmax,
                                                 u64* __restrict__ Sb,
                                                 u64* __restrict__ Wb) {
#pragma clang fp contract(off)
    const int tid = threadIdx.x;
    const int b = blockIdx.x >> 10;
    const int y = blockIdx.x & (H - 1);
    const float hi = (*thinmax) * 0.15f;

    const float4 t4 = *(const float4*)&thin[(size_t)blockIdx.x * 1024 + tid * 4];
    float tvals[4] = {t4.x, t4.y, t4.z, t4.w};
    unsigned int nibS = 0, nibW = 0;
#pragma unroll
    for (int j = 0; j < 4; ++j) {
        bool strong = (tvals[j] >= hi);
        bool weak = (!strong) && (tvals[j] >= 0.00392f);
        nibS |= (strong ? 1u : 0u) << j;
        nibW |= (weak ? 1u : 0u) << j;
    }
    __shared__ unsigned char ns[256], nw[256];
    ns[tid] = (unsigned char)nibS;
    nw[tid] = (unsigned char)nibW;
    __syncthreads();

    if (tid < 16) {
        u64 sw = 0, ww = 0;
#pragma unroll
        for (int j = 0; j < 16; ++j) {
            sw |= (u64)ns[tid * 16 + j] << (4 * j);
            ww |= (u64)nw[tid * 16 + j] << (4 * j);
        }
        const int ty = y >> 6, row = y & 63;
        const int widx = ((b << 8) | (ty << 4) | tid) * 64 + row;
        Sb[widx] = sw;
        Wb[widx] = ww;
    }
}

// ---------------- hysteresis: bit-parallel 64x64 tile per wave, tile-major ----------------
__global__ __launch_bounds__(256) void k_hyster_bits(const u64* __restrict__ Wb,
                                                     u64* __restrict__ Sb) {
    const int lane = threadIdx.x & 63;
    const int t = blockIdx.x * 4 + (threadIdx.x >> 6);  // global tile id = b*256+ty*16+tx
    const int ty = (t >> 4) & 15;
    const int tx = t & 15;
    const int idx = t * 64 + lane;

    u64 S = Sb[idx];
    const u64 Wk = Wb[idx];

    // static horizontal halo bits (left/right neighbor tiles, same row)
    u64 hstat = 0;
    if (tx > 0)  hstat |= (Sb[(t - 1) * 64 + lane] >> 63) & 1ull;
    if (tx < 15) hstat |= (Sb[(t + 1) * 64 + lane] & 1ull) << 63;

    // static vertical halo for lane 0 (row above tile) / lane 63 (row below)
    u64 halo = 0;
    if (lane == 0 && ty > 0) {
        const int ta = t - 16;
        u64 tc = Sb[ta * 64 + 63];
        u64 hh = (tc << 1) | tc | (tc >> 1);
        if (tx > 0)  hh |= (Sb[(ta - 1) * 64 + 63] >> 63) & 1ull;
        if (tx < 15) hh |= (Sb[(ta + 1) * 64 + 63] & 1ull) << 63;
        halo = hh;
    }
    if (lane == 63 && ty < 15) {
        const int tb = t + 16;
        u64 tc = Sb[tb * 64 + 0];
        u64 hh = (tc << 1) | tc | (tc >> 1);
        if (tx > 0)  hh |= (Sb[(tb - 1) * 64 + 0] >> 63) & 1ull;
        if (tx < 15) hh |= (Sb[(tb + 1) * 64 + 0] & 1ull) << 63;
        halo = hh;
    }

    for (int it = 0; it < 160; ++it) {
        u64 h = (S << 1) | S | (S >> 1) | hstat;
        u64 up = __shfl_up(h, 1, 64);
        if (lane == 0) up = halo;
        u64 dn = __shfl_down(h, 1, 64);
        if (lane == 63) dn = halo;
        u64 dil = h | up | dn;
        u64 nS = S | (Wk & dil);
        bool ch = (nS != S);
        S = nS;
        if (!__any(ch)) break;
    }

    Sb[idx] = S;
}

// ---------------- finalize: strong bit -> 255 else 0, float4 stores ----------------
__global__ __launch_bounds__(256) void k_final4(const u64* __restrict__ Sb,
                                                float* __restrict__ out) {
    const int gid = blockIdx.x * 256 + threadIdx.x;
    const int p0 = gid * 4;
    const int x = p0 & (W - 1);
    const int y = (p0 >> 10) & (H - 1);
    const int b = p0 >> 20;
    const int widx = ((b << 8) | ((y >> 6) << 4) | (x >> 6)) * 64 + (y & 63);
    const u64 w = Sb[widx];
    const unsigned int nib = (unsigned int)((w >> (x & 63)) & 0xFull);
    float4 o;
    o.x = (nib & 1u) ? 255.0f : 0.0f;
    o.y = (nib & 2u) ? 255.0f : 0.0f;
    o.z = (nib & 4u) ? 255.0f : 0.0f;
    o.w = (nib & 8u) ? 255.0f : 0.0f;
    *(float4*)&out[p0] = o;
}

extern "C" void kernel_launch(void* const* d_in, const int* in_sizes, int n_in,
                              void* d_out, int out_size, void* d_ws, size_t ws_size,
                              hipStream_t stream) {
    (void)in_sizes; (void)n_in; (void)out_size; (void)ws_size;
    const float* img = (const float*)d_in[0];
    float* out = (float*)d_out;

    // workspace layout
    float* hdr = (float*)d_ws;                                    // [0..15]=magmax, [16]=thinmax
    float* partialA = (float*)((char*)d_ws + 256);                // 4096 floats (K1 blocks)
    float* partialB = partialA + 4096;                            // 16384 floats (nms blocks)
    float* A = partialB + 16384;                                  // mag, 64 MB (16B-aligned)
    unsigned char* C = (unsigned char*)(A + (size_t)NTOT);        // bucket, 16 MB
    u64* Sb = (u64*)(C + (size_t)NTOT);                           // strong bits, 2 MB
    u64* Wb = Sb + NTOT / 64;                                     // weak bits, 2 MB

    dim3 blk(256);
    k_smooth_sobel<<<dim3(W / TW, H / TH, BB), blk, 0, stream>>>(img, A, C, partialA);
    k_redmax_img<<<dim3(BB), blk, 0, stream>>>(partialA, hdr);
    k_nms4<<<dim3(NTOT / 1024), blk, 0, stream>>>(A, C, hdr, out, partialB);  // out = thin
    k_redmax_all<<<dim3(1), dim3(1024), 0, stream>>>(partialB, hdr + 16);
    k_thresh4<<<dim3(NTOT / 1024), blk, 0, stream>>>(out, hdr + 16, Sb, Wb);
    for (int p = 0; p < 6; ++p)
        k_hyster_bits<<<dim3(NTOT / (64 * 64) / 4), blk, 0, stream>>>(Wb, Sb);
    k_final4<<<dim3(NTOT / 1024), blk, 0, stream>>>(Sb, out);
}

// Round 6
// 264.608 us; speedup vs baseline: 12.8591x; 1.2271x over previous
//
#include <hip/hip_runtime.h>
#include <math.h>

#define BB 16
#define H 1024
#define W 1024
#define HW (H*W)
#define NTOT (BB*HW)

typedef unsigned long long u64;

// float32 of np.exp(-0.5*(n/1)^2), n=-2..2 (correctly-rounded decimal literals)
__device__ __constant__ float GW[5] = {
    0.13533528323661270f, 0.60653065971263342f, 1.0f,
    0.60653065971263342f, 0.13533528323661270f};

// NMS neighbor offsets per direction bucket
// 0:E 1:SE 2:S 3:SW 4:W 5:NW 6:N 7:NE
__device__ __constant__ int NBDY[8] = {0, 1, 1, 1, 0, -1, -1, -1};
__device__ __constant__ int NBDX[8] = {1, 1, 0, -1, -1, -1, 0, 1};

#define CSCALE ((float)(180.0 / 3.1415926))

// Cephes atanf core: input in [0,1], error ~1e-7 rad
__device__ __forceinline__ float atan_poly01(float xin) {
    float y0 = 0.0f, x = xin;
    if (xin > 0.41421356f) {
        x = __fdividef(xin - 1.0f, xin + 1.0f);
        y0 = 0.78539816339f;  // pi/4
    }
    float z = x * x;
    float p = ((8.05374449538e-2f * z - 1.38776856032e-1f) * z + 1.99777106478e-1f) * z
              - 3.33329491539e-1f;
    return y0 + (p * z * x + x);
}

// =====================================================================
// K1: fused gaussian(h)+gaussian(v)+sobel+mag+bucket + per-block magmax
// Tile: 128 wide x 16 high. LDS 24.6 KB -> 6 blocks/CU.
// =====================================================================
#define TW 128
#define TH 16
// sA: img rows y0-3..y0+18 (22), cols x0-4..x0+131 (136), stride 136
// sB: gh  rows y0-3..y0+18 (22), cols x0-1..x0+130 (130 used), stride 132
// sm overlays sA: rows y0-1..y0+16 (18), cols x0-1..x0+128 (130 used)
__global__ __launch_bounds__(256, 6) void k_smooth_sobel(const float* __restrict__ img,
                                                         float* __restrict__ mag,
                                                         unsigned char* __restrict__ bucket,
                                                         float* __restrict__ partial) {
#pragma clang fp contract(off)
    __shared__ float sA[22 * 136];
    __shared__ float sB[22 * 132];
    __shared__ float red[256];

    const int tid = threadIdx.x;
    const int x0 = blockIdx.x * TW;
    const int y0 = blockIdx.y * TH;
    const int b = blockIdx.z;
    const size_t base = (size_t)b * HW;

    // ---- stage A: load img tile + halo (float4, all-or-nothing per vec) ----
    for (int idx = tid; idx < 22 * 34; idx += 256) {
        int r = idx / 34, v = idx % 34;
        int gy = y0 - 3 + r;
        int gxv = x0 - 4 + v * 4;
        float4 val = make_float4(0.f, 0.f, 0.f, 0.f);
        if (gy >= 0 && gy < H && gxv >= 0 && gxv <= W - 4)
            val = *(const float4*)&img[base + (size_t)gy * W + gxv];
        *(float4*)&sA[r * 136 + v * 4] = val;
    }
    __syncthreads();

    // ---- stage B: horizontal gaussian -> sB ----
    // sB col c <-> global x0-1+c ; sA col j <-> global x0-4+j, so taps are sA cols c+1..c+5
    for (int idx = tid; idx < 22 * 130; idx += 256) {
        int r = idx / 130, c = idx % 130;
        const float* row = &sA[r * 136 + c + 1];
        float s = 0.0f;
#pragma unroll
        for (int k = 0; k < 5; ++k) s = s + GW[k] * row[k];
        sB[r * 132 + c] = s;
    }
    __syncthreads();

    // ---- stage C: vertical gaussian -> sm (overlays sA) ----
    // sm row rr <-> global y0-1+rr, taps are sB rows rr..rr+4; sm col c <-> global x0-1+c
    for (int idx = tid; idx < 18 * 130; idx += 256) {
        int rr = idx / 130, c = idx % 130;
        float s = 0.0f;
#pragma unroll
        for (int k = 0; k < 5; ++k) s = s + GW[k] * sB[(rr + k) * 132 + c];
        sA[rr * 136 + c] = s;
    }
    __syncthreads();

    // ---- stage D: sobel + mag + bucket, 4 px/thread-iter, float4 stores ----
    // sm(y+dy, x+dx) = sA[(r+1+dy)*136 + (c+1+dx)]  (sm tile offset is -1,-1)
    float tmax = 0.0f;
#pragma unroll
    for (int k2 = 0; k2 < 2; ++k2) {
        int v = tid + k2 * 256;          // 0..511
        int r = v >> 5;                  // 0..15
        int cg4 = (v & 31) * 4;
        int y = y0 + r;
        const bool ym = (y > 0), yp = (y < H - 1);

        float mg[4];
        unsigned int bk = 0;
#pragma unroll
        for (int j = 0; j < 4; ++j) {
            int c = cg4 + j;
            int x = x0 + c;
            const bool xm = (x > 0), xp = (x < W - 1);

            float a00 = 0.f, a01 = 0.f, a02 = 0.f, a10 = 0.f, a12 = 0.f,
                  a20 = 0.f, a21 = 0.f, a22 = 0.f;
            if (ym) {
                if (xm) a00 = sA[r * 136 + c];
                a01 = sA[r * 136 + c + 1];
                if (xp) a02 = sA[r * 136 + c + 2];
            }
            if (xm) a10 = sA[(r + 1) * 136 + c];
            if (xp) a12 = sA[(r + 1) * 136 + c + 2];
            if (yp) {
                if (xm) a20 = sA[(r + 2) * 136 + c];
                a21 = sA[(r + 2) * 136 + c + 1];
                if (xp) a22 = sA[(r + 2) * 136 + c + 2];
            }

            float Ix = a00;
            Ix = Ix - a02;
            Ix = Ix + 2.0f * a10;
            Ix = Ix - 2.0f * a12;
            Ix = Ix + a20;
            Ix = Ix - a22;

            float Iy = a00;
            Iy = Iy + 2.0f * a01;
            Iy = Iy + a02;
            Iy = Iy - a20;
            Iy = Iy - 2.0f * a21;
            Iy = Iy - a22;

            float t1 = Ix * Ix;
            float t2 = Iy * Iy;
            float m = sqrtf(t1 + t2);
            mg[j] = m;
            tmax = fmaxf(tmax, m);

            // fast octant classification; exact double fallback near boundaries
            float ax = fabsf(Ix), ay = fabsf(Iy);
            float mn = fminf(ax, ay), mx = fmaxf(ax, ay);
            float zr = __fdividef(mn, mx);
            float bse = atan_poly01(zr);
            float phi = (ay > ax) ? (1.57079632679f - bse) : bse;
            if (Ix < 0.0f) phi = 3.14159265359f - phi;
            float theta = (Iy >= 0.0f) ? phi : -phi;
            float t = (theta * CSCALE + 180.0f) * (1.0f / 45.0f);
            float rr2 = rintf(t);
            if ((mx < 1e-30f) || (0.5f - fabsf(t - rr2) < 1e-4f)) {
                float fa2 = (float)atan2((double)Iy, (double)Ix);
                float d2 = fa2 * CSCALE;
                d2 = d2 + 180.0f;
                float t2d = d2 / 45.0f;
                rr2 = rintf(t2d);
            }
            int bidx = ((int)rr2) % 8;
            bk |= ((unsigned int)bidx) << (8 * j);
        }
        *(float4*)&mag[base + (size_t)y * W + x0 + cg4] = make_float4(mg[0], mg[1], mg[2], mg[3]);
        *(unsigned int*)&bucket[base + (size_t)y * W + x0 + cg4] = bk;
    }

    red[tid] = tmax;
    __syncthreads();
    for (int s = 128; s > 0; s >>= 1) {
        if (tid < s) red[tid] = fmaxf(red[tid], red[tid + s]);
        __syncthreads();
    }
    if (tid == 0) {
        int pb = (blockIdx.z * 64 + blockIdx.y) * 8 + blockIdx.x;  // 512 per image
        partial[pb] = red[0];
    }
}

// ---------------- per-image max over 512 block partials ----------------
__global__ __launch_bounds__(256) void k_redmax_img(const float* __restrict__ partial,
                                                    float* __restrict__ magmax) {
    __shared__ float red[256];
    const float* p = partial + blockIdx.x * 512;
    float m = fmaxf(p[threadIdx.x], p[threadIdx.x + 256]);
    red[threadIdx.x] = m;
    __syncthreads();
    for (int s = 128; s > 0; s >>= 1) {
        if (threadIdx.x < s) red[threadIdx.x] = fmaxf(red[threadIdx.x], red[threadIdx.x + s]);
        __syncthreads();
    }
    if (threadIdx.x == 0) magmax[blockIdx.x] = red[0];
}

// ---------------- global max over 4096 nms-block partials ----------------
__global__ __launch_bounds__(1024) void k_redmax_all(const float* __restrict__ partial,
                                                     float* __restrict__ thinmax) {
    __shared__ float red[1024];
    float m = 0.0f;
    for (int k = threadIdx.x; k < 4096; k += 1024) m = fmaxf(m, partial[k]);
    red[threadIdx.x] = m;
    __syncthreads();
    for (int s = 512; s > 0; s >>= 1) {
        if (threadIdx.x < s) red[threadIdx.x] = fmaxf(red[threadIdx.x], red[threadIdx.x + s]);
        __syncthreads();
    }
    if (threadIdx.x == 0) *thinmax = red[0];
}

// =====================================================================
// NMS: LDS tile of pre-normalized magnitude (mag/M staged once),
// gathers from LDS, 16 px/thread. Tile 128x32 + halo.
// sN col j <-> global x0-4+j  =>  pixel x0+c is at col c+4.
// sN row r' <-> global y0-1+r' =>  pixel y0+r is at row r+1.
// =====================================================================
__global__ __launch_bounds__(256, 8) void k_nms_t(const float* __restrict__ mag,
                                                  const unsigned char* __restrict__ bucket,
                                                  const float* __restrict__ magmax,
                                                  float* __restrict__ thin,
                                                  float* __restrict__ partial) {
#pragma clang fp contract(off)
    __shared__ float sN[34 * 136];
    __shared__ float red[256];

    const int tid = threadIdx.x;
    const int x0 = blockIdx.x * 128;
    const int y0 = blockIdx.y * 32;
    const int b = blockIdx.z;
    const size_t base = (size_t)b * HW;
    const float M = magmax[b];

    // stage normalized tile + halo; zero outside image (matches conv zero-pad)
    for (int idx = tid; idx < 34 * 34; idx += 256) {
        int r = idx / 34, v = idx % 34;
        int gy = y0 - 1 + r;
        int gxv = x0 - 4 + v * 4;
        float4 val = make_float4(0.f, 0.f, 0.f, 0.f);
        if (gy >= 0 && gy < H && gxv >= 0 && gxv <= W - 4)
            val = *(const float4*)&mag[base + (size_t)gy * W + gxv];
        val.x = val.x / M;  // IEEE divide, replicates reference normalization
        val.y = val.y / M;
        val.z = val.z / M;
        val.w = val.w / M;
        *(float4*)&sN[r * 136 + v * 4] = val;
    }
    __syncthreads();

    float tmax = 0.0f;
#pragma unroll
    for (int k4 = 0; k4 < 4; ++k4) {
        int v = tid + k4 * 256;          // 0..1023
        int r = v >> 5;                  // 0..31
        int cg4 = (v & 31) * 4;
        int y = y0 + r;

        unsigned int bk = *(const unsigned int*)&bucket[base + (size_t)y * W + x0 + cg4];
        float tv[4];
#pragma unroll
        for (int j = 0; j < 4; ++j) {
            int c = cg4 + j;
            int idx = (bk >> (8 * j)) & 0xff;
            int dy = NBDY[idx], dx = NBDX[idx];
            float mp = sN[(r + 1) * 136 + c + 4];
            float npv = sN[(r + 1 + dy) * 136 + c + 4 + dx];
            float nnv = sN[(r + 1 - dy) * 136 + c + 4 - dx];
            float cs_p = mp - npv;
            float cs_n = mp - nnv;
            tv[j] = (fminf(cs_p, cs_n) > 0.0f) ? mp : 0.0f;
            tmax = fmaxf(tmax, tv[j]);
        }
        *(float4*)&thin[base + (size_t)y * W + x0 + cg4] = make_float4(tv[0], tv[1], tv[2], tv[3]);
    }

    red[tid] = tmax;
    __syncthreads();
    for (int s = 128; s > 0; s >>= 1) {
        if (tid < s) red[tid] = fmaxf(red[tid], red[tid + s]);
        __syncthreads();
    }
    if (tid == 0) {
        int pb = (blockIdx.z * 32 + blockIdx.y) * 8 + blockIdx.x;  // 256 per image
        partial[pb] = red[0];
    }
}

// ---------------- double threshold -> tile-major packed bitmasks ----------------
// word index = (b*256 + ty*16 + tx)*64 + (y&63). One block = one image row.
__global__ __launch_bounds__(256) void k_thresh4(const float* __restrict__ thin,
                                                 const float* __restrict__ thinmax,
                                                 u64* __restrict__ Sb,
                                                 u64* __restrict__ Wb) {
#pragma clang fp contract(off)
    const int tid = threadIdx.x;
    const int b = blockIdx.x >> 10;
    const int y = blockIdx.x & (H - 1);
    const float hi = (*thinmax) * 0.15f;

    const float4 t4 = *(const float4*)&thin[(size_t)blockIdx.x * 1024 + tid * 4];
    float tvals[4] = {t4.x, t4.y, t4.z, t4.w};
    unsigned int nibS = 0, nibW = 0;
#pragma unroll
    for (int j = 0; j < 4; ++j) {
        bool strong = (tvals[j] >= hi);
        bool weak = (!strong) && (tvals[j] >= 0.00392f);
        nibS |= (strong ? 1u : 0u) << j;
        nibW |= (weak ? 1u : 0u) << j;
    }
    __shared__ unsigned char ns[256], nw[256];
    ns[tid] = (unsigned char)nibS;
    nw[tid] = (unsigned char)nibW;
    __syncthreads();

    if (tid < 16) {
        u64 sw = 0, ww = 0;
#pragma unroll
        for (int j = 0; j < 16; ++j) {
            sw |= (u64)ns[tid * 16 + j] << (4 * j);
            ww |= (u64)nw[tid * 16 + j] << (4 * j);
        }
        const int ty = y >> 6, row = y & 63;
        const int widx = ((b << 8) | (ty << 4) | tid) * 64 + row;
        Sb[widx] = sw;
        Wb[widx] = ww;
    }
}

// ---------------- hysteresis: bit-parallel 64x64 tile per wave, tile-major ----------------
__global__ __launch_bounds__(256) void k_hyster_bits(const u64* __restrict__ Wb,
                                                     u64* __restrict__ Sb) {
    const int lane = threadIdx.x & 63;
    const int t = blockIdx.x * 4 + (threadIdx.x >> 6);  // global tile id = b*256+ty*16+tx
    const int ty = (t >> 4) & 15;
    const int tx = t & 15;
    const int idx = t * 64 + lane;

    u64 S = Sb[idx];
    const u64 Wk = Wb[idx];

    u64 hstat = 0;
    if (tx > 0)  hstat |= (Sb[(t - 1) * 64 + lane] >> 63) & 1ull;
    if (tx < 15) hstat |= (Sb[(t + 1) * 64 + lane] & 1ull) << 63;

    u64 halo = 0;
    if (lane == 0 && ty > 0) {
        const int ta = t - 16;
        u64 tc = Sb[ta * 64 + 63];
        u64 hh = (tc << 1) | tc | (tc >> 1);
        if (tx > 0)  hh |= (Sb[(ta - 1) * 64 + 63] >> 63) & 1ull;
        if (tx < 15) hh |= (Sb[(ta + 1) * 64 + 63] & 1ull) << 63;
        halo = hh;
    }
    if (lane == 63 && ty < 15) {
        const int tb = t + 16;
        u64 tc = Sb[tb * 64 + 0];
        u64 hh = (tc << 1) | tc | (tc >> 1);
        if (tx > 0)  hh |= (Sb[(tb - 1) * 64 + 0] >> 63) & 1ull;
        if (tx < 15) hh |= (Sb[(tb + 1) * 64 + 0] & 1ull) << 63;
        halo = hh;
    }

    for (int it = 0; it < 160; ++it) {
        u64 h = (S << 1) | S | (S >> 1) | hstat;
        u64 up = __shfl_up(h, 1, 64);
        if (lane == 0) up = halo;
        u64 dn = __shfl_down(h, 1, 64);
        if (lane == 63) dn = halo;
        u64 dil = h | up | dn;
        u64 nS = S | (Wk & dil);
        bool ch = (nS != S);
        S = nS;
        if (!__any(ch)) break;
    }

    Sb[idx] = S;
}

// ---------------- finalize: strong bit -> 255 else 0, float4 stores ----------------
__global__ __launch_bounds__(256) void k_final4(const u64* __restrict__ Sb,
                                                float* __restrict__ out) {
    const int gid = blockIdx.x * 256 + threadIdx.x;
    const int p0 = gid * 4;
    const int x = p0 & (W - 1);
    const int y = (p0 >> 10) & (H - 1);
    const int b = p0 >> 20;
    const int widx = ((b << 8) | ((y >> 6) << 4) | (x >> 6)) * 64 + (y & 63);
    const u64 w = Sb[widx];
    const unsigned int nib = (unsigned int)((w >> (x & 63)) & 0xFull);
    float4 o;
    o.x = (nib & 1u) ? 255.0f : 0.0f;
    o.y = (nib & 2u) ? 255.0f : 0.0f;
    o.z = (nib & 4u) ? 255.0f : 0.0f;
    o.w = (nib & 8u) ? 255.0f : 0.0f;
    *(float4*)&out[p0] = o;
}

extern "C" void kernel_launch(void* const* d_in, const int* in_sizes, int n_in,
                              void* d_out, int out_size, void* d_ws, size_t ws_size,
                              hipStream_t stream) {
    (void)in_sizes; (void)n_in; (void)out_size; (void)ws_size;
    const float* img = (const float*)d_in[0];
    float* out = (float*)d_out;

    // workspace layout
    float* hdr = (float*)d_ws;                                    // [0..15]=magmax, [16]=thinmax
    float* partialA = (float*)((char*)d_ws + 256);                // 8192 floats (K1 blocks)
    float* partialB = partialA + 8192;                            // 4096 floats (nms blocks)
    float* A = partialB + 4096;                                   // mag, 64 MB (16B-aligned)
    unsigned char* C = (unsigned char*)(A + (size_t)NTOT);        // bucket, 16 MB
    u64* Sb = (u64*)(C + (size_t)NTOT);                           // strong bits, 2 MB
    u64* Wb = Sb + NTOT / 64;                                     // weak bits, 2 MB

    dim3 blk(256);
    k_smooth_sobel<<<dim3(W / TW, H / TH, BB), blk, 0, stream>>>(img, A, C, partialA);
    k_redmax_img<<<dim3(BB), blk, 0, stream>>>(partialA, hdr);
    k_nms_t<<<dim3(8, 32, BB), blk, 0, stream>>>(A, C, hdr, out, partialB);  // out = thin
    k_redmax_all<<<dim3(1), dim3(1024), 0, stream>>>(partialB, hdr + 16);
    k_thresh4<<<dim3(NTOT / 1024), blk, 0, stream>>>(out, hdr + 16, Sb, Wb);
    for (int p = 0; p < 6; ++p)
        k_hyster_bits<<<dim3(NTOT / (64 * 64) / 4), blk, 0, stream>>>(Wb, Sb);
    k_final4<<<dim3(NTOT / 1024), blk, 0, stream>>>(Sb, out);
}